// Round 6
// baseline (12.282 us; speedup 1.0000x reference)
//
#include <hip/hip_runtime.h>
#include <math.h>

#define TB_COLS  16
#define TB_ROWS  32
#define HALO     8
#define WIN_R    (TB_ROWS + 2 * HALO)     // 48 rows staged per block
#define HUGE_BEST 0x20000000

// Exact full-row fallback (rare: P ~ 2^-17 per row on random data, or
// pathological inputs). Scans global mask row gy2 outward from column x,
// updating best with min over dx of dy2 + dx^2 for opposite-class cells.
__device__ __forceinline__ void row_scan(const float* __restrict__ maskb,
                                         int gy2, int x, bool fg,
                                         int dy2, int& best)
{
    const float* rowp = maskb + (size_t)gy2 * 512;
    for (int dx = 0; dy2 + dx * dx < best; ++dx) {
        int xr = x + dx, xl = x - dx;
        bool hit = false;
        if (xr < 512) { float m = rowp[xr]; hit = fg ? (m != 1.0f) : (m == 1.0f); }
        if (xl >= 0)  { float m = rowp[xl]; hit |= (fg ? (m != 1.0f) : (m == 1.0f)); }
        if (hit) { best = min(best, dy2 + dx * dx); break; }  // first hit = row min
        if (xr >= 512 && xl < 0) break;                        // row exhausted
    }
}

// ---------------------------------------------------------------------------
// Direct exact SDF: out = fg ? -dist(nearest bg) : +dist(nearest fg).
// Identical to the separable two-pass EDT (min over opposite-class pixels of
// dy^2+dx^2); integer-exact => bit-identical to the fp32 reference.
// Block = 16x32 output tile. Mask window (48 rows x 32 cols) staged as 48 u32
// BITMASKS via ballots (192 B LDS). Per pixel: expand dy while dy^2 < best;
// per row, nearest opposite column in O(1) via ctz/clz on the row bitmask.
// d <= 8 is provably the exact row min (window reach >= 8 on both sides);
// otherwise the exact global row_scan fallback fires (essentially never).
// No workspace, no inter-block dependency, single dispatch.
// ---------------------------------------------------------------------------
__global__ __launch_bounds__(256)
void sdf_direct(const float* __restrict__ mask, float* __restrict__ out)
{
    __shared__ unsigned fgbits[WIN_R];

    const int t    = threadIdx.x;
    const int wid  = t >> 6;
    const int lane = t & 63;

    const int img = blockIdx.x >> 9;          // 512 blocks per image
    const int rem = blockIdx.x & 511;
    const int x0  = (rem >> 4) * TB_COLS;     // strip 0..31
    const int y0  = (rem & 15) * TB_ROWS;     // ychunk 0..15
    const float* maskb = mask + (size_t)img * 262144;

    // ---- stage 48-row x 32-col window as bitmasks (1 u32 per row) ----
    {
        const int i  = t & 31;                // window column 0..31
        const int rp = t >> 5;                // 0..7
#pragma unroll
        for (int kk = 0; kk < 6; ++kk) {
            int rr  = rp + kk * 8;            // 0..47
            int gy2 = y0 - HALO + rr;
            int xw  = x0 - HALO + i;
            bool bit = false;
            if ((unsigned)gy2 < 512u && (unsigned)xw < 512u)
                bit = (maskb[(size_t)gy2 * 512 + xw] == 1.0f);
            unsigned long long bl = __ballot(bit);   // lanes 0-31: row 2*wid; 32-63: 2*wid+1
            if (lane == 0)  fgbits[2 * wid + kk * 8]     = (unsigned)bl;
            if (lane == 32) fgbits[2 * wid + 1 + kk * 8] = (unsigned)(bl >> 32);
        }
    }
    __syncthreads();

    // block-uniform valid-column mask (window cols x0-8 .. x0+23)
    unsigned valid = 0xFFFFFFFFu;
    if (x0 == 0)             valid &= 0xFFFFFF00u;   // cols < 0
    if (x0 == 512 - TB_COLS) valid &= 0x00FFFFFFu;   // cols >= 512

    const int c  = t & 15;                    // column within tile
    const int rg = t >> 4;                    // 0..15
    const int px = HALO + c;                  // pixel's bit position (8..23)
    const int gx = x0 + c;

#pragma unroll
    for (int k = 0; k < 2; ++k) {
        const int ycl  = rg + k * 16;         // tile row 0..31
        const int yloc = ycl + HALO;          // window row 8..39
        const int gy   = y0 + ycl;
        const bool fg  = (fgbits[yloc] >> px) & 1;
        int best = HUGE_BEST;

        auto do_row = [&](int dy) {
            int gy2 = gy + dy;
            if ((unsigned)gy2 >= 512u) return;
            int dy2 = dy * dy;
            if (dy2 >= best) return;
            if (dy >= -HALO && dy <= HALO) {
                unsigned f   = fgbits[yloc + dy];
                unsigned cnd = fg ? (~f & valid) : f;   // opposite-class cells
                int d = 99;
                unsigned hi = cnd >> px;                // dx >= 0 (bit0 = own col, never set)
                unsigned lo = cnd << (31 - px);         // dx > 0 leftward
                if (hi) d = __builtin_ctz(hi);
                if (lo) d = min(d, __builtin_clz(lo));
                if (d <= HALO) {
                    best = min(best, dy2 + d * d);      // exact row min
                } else if (dy2 + (HALO + 1) * (HALO + 1) < best) {
                    row_scan(maskb, gy2, gx, fg, dy2, best);  // rare exact fallback
                }
                // else: row min >= dy2+81 >= best, cannot improve
            } else {
                row_scan(maskb, gy2, gx, fg, dy2, best);      // beyond window (rare)
            }
        };

        do_row(0);
        for (int dy = 1; dy < 512 && dy * dy < best; ++dy) {
            do_row(dy);
            do_row(-dy);
        }

        // no-opposite-class sentinel: reference yields exactly 1e12 -> sqrt
        float fb   = (best >= HUGE_BEST) ? 1e12f : (float)best;
        float dist = sqrtf(fb);
        out[((size_t)img * 512 + gy) * 512 + gx] = fg ? -dist : dist;
    }
}

extern "C" void kernel_launch(void* const* d_in, const int* in_sizes, int n_in,
                              void* d_out, int out_size, void* d_ws, size_t ws_size,
                              hipStream_t stream) {
    const float* mask = (const float*)d_in[0];
    float* out = (float*)d_out;
    const int total  = in_sizes[0];           // B*512*512
    const int nblk   = (total >> 18) << 9;    // B * 512 blocks (16x32 tiles)

    sdf_direct<<<nblk, 256, 0, stream>>>(mask, out);
}

// Round 7
// 9.547 us; speedup vs baseline: 1.2865x; 1.2865x over previous
//
#include <hip/hip_runtime.h>
#include <math.h>

#define TB_COLS 16
#define TB_ROWS 32
#define HX 8                               // x reach of the u32 row window
#define HY 4                               // staged y halo (branchless uses +/-3)
#define WIN_R (TB_ROWS + 2 * HY)           // 40 rows staged
#define HUGE_BEST 0x20000000

// Exact full-row scan on global memory (cold path; P ~ 2^-44 per pixel on
// random data, or pathological inputs). First hit while expanding |dx| IS the
// row min.
__device__ __forceinline__ void row_scan(const float* __restrict__ rowp,
                                         int x, bool fg, int dy2, int& best)
{
    for (int dx = 0; dy2 + dx * dx < best; ++dx) {
        int xr = x + dx, xl = x - dx;
        bool hit = false;
        if (xr < 512) { float m = rowp[xr]; hit = fg ? (m != 1.0f) : (m == 1.0f); }
        if (xl >= 0)  { float m = rowp[xl]; hit |= (fg ? (m != 1.0f) : (m == 1.0f)); }
        if (hit) { best = min(best, dy2 + dx * dx); break; }
        if (xr >= 512 && xl < 0) break;
    }
}

// ---------------------------------------------------------------------------
// Direct exact SDF, branchless hot path.
// Block = 16x32 output tile. 40-row x 32-col mask window staged as TWO bitmask
// arrays (fg bits, bg bits; border masking folded in) -> per-row candidate
// word is ONE LDS read. Per pixel: unrolled dy in [-3..3], nearest opposite
// column per row via ffbl/ffbh on the shifted word. Every contribution is a
// real candidate distance, so best <= 15 certifies exactness (excluded region:
// |dy|>=4 -> >=16, |dx|>=9 -> >=81). Else: exact global fallback (never taken
// on random data). Bit-identical to the fp32 reference (integer-exact + same
// 1e12 sentinel).
// ---------------------------------------------------------------------------
__global__ __launch_bounds__(256)
void sdf_direct(const float* __restrict__ mask, float* __restrict__ out)
{
    __shared__ unsigned pairs[WIN_R * 2];  // [row*2+0]=fg bits, [row*2+1]=bg bits

    const int t    = threadIdx.x;
    const int lane = t & 63;
    const int wid  = t >> 6;

    const int img = blockIdx.x >> 9;       // 512 blocks per image
    const int rem = blockIdx.x & 511;
    const int x0  = (rem >> 4) * TB_COLS;  // strip 0..31
    const int y0  = (rem & 15) * TB_ROWS;  // ychunk 0..15
    const float* maskb = mask + (size_t)img * 262144;

    unsigned valid = 0xFFFFFFFFu;          // in-image columns of the 32-col window
    if (x0 == 0)             valid &= 0xFFFFFF00u;
    if (x0 == 512 - TB_COLS) valid &= 0x00FFFFFFu;

    // ---- stage 40 rows: 5 rounds x (4 waves x 2 rows per ballot) ----
#pragma unroll
    for (int kk = 0; kk < 5; ++kk) {
        int rrA = kk * 8 + 2 * wid;        // row of lanes 0..31 this round
        int rr  = rrA + (lane >> 5);       // this lane's row
        int gy  = y0 - HY + rr;
        int xw  = x0 - HX + (lane & 31);
        bool bit = false;
        if ((unsigned)gy < 512u && (unsigned)xw < 512u)
            bit = (maskb[(size_t)gy * 512 + xw] == 1.0f);
        unsigned long long bl = __ballot(bit);   // lo32: row rrA, hi32: row rrA+1
        if (lane < 4) {
            int r2 = rrA + (lane >> 1);
            unsigned fgw = (lane >> 1) ? (unsigned)(bl >> 32) : (unsigned)bl;
            int gy2 = y0 - HY + r2;
            unsigned vm = ((unsigned)gy2 < 512u) ? valid : 0u;
            pairs[r2 * 2 + (lane & 1)] = (lane & 1) ? (~fgw & vm) : fgw;
        }
    }
    __syncthreads();

    const int c   = t & 15;                // column within tile
    const int rg  = t >> 4;                // 0..15
    const int px  = HX + c;                // pixel's bit position (8..23)
    const int shl = 31 - px;
    const int gx  = x0 + c;

#pragma unroll
    for (int k = 0; k < 2; ++k) {
        const int ycl  = rg + k * 16;      // tile row 0..31
        const int yloc = ycl + HY;         // window row 4..35
        const int gy   = y0 + ycl;
        const bool fg  = (pairs[yloc * 2] >> px) & 1;
        const unsigned* sel = &pairs[fg ? 1 : 0];   // opposite-class bit rows

        int best = HUGE_BEST;
#pragma unroll
        for (int dy = -3; dy <= 3; ++dy) { // branchless: 7 rows, no early exit
            unsigned cnd = sel[(yloc + dy) * 2];
            unsigned hi  = cnd >> px;               // dx >= 0 (bit0 = own col, never set)
            unsigned lo  = cnd << shl;              // dx >= 0 leftward (bit31 = own col)
            unsigned dhi = hi ? (unsigned)__builtin_ctz(hi) : 32u;
            unsigned dlo = lo ? (unsigned)__builtin_clz(lo) : 32u;
            unsigned d   = min(dhi, dlo);           // true nearest within window
            best = min(best, dy * dy + (int)(d * d));
        }

        if (__builtin_expect(best > 15, 0)) {
            // cold exact fallback: recompute from scratch on global memory
            best = HUGE_BEST;
            row_scan(maskb + (size_t)gy * 512, gx, fg, 0, best);
            for (int dy = 1; dy < 512 && dy * dy < best; ++dy) {
                int yu = gy + dy, yd = gy - dy;
                if (yu < 512) row_scan(maskb + (size_t)yu * 512, gx, fg, dy * dy, best);
                if (yd >= 0)  row_scan(maskb + (size_t)yd * 512, gx, fg, dy * dy, best);
            }
        }

        // no-opposite-class sentinel: reference yields exactly sqrt(1e12)
        float fb   = (best >= HUGE_BEST) ? 1e12f : (float)best;
        float dist = sqrtf(fb);
        out[((size_t)img * 512 + gy) * 512 + gx] = fg ? -dist : dist;
    }
}

extern "C" void kernel_launch(void* const* d_in, const int* in_sizes, int n_in,
                              void* d_out, int out_size, void* d_ws, size_t ws_size,
                              hipStream_t stream) {
    const float* mask = (const float*)d_in[0];
    float* out = (float*)d_out;
    const int total = in_sizes[0];         // B*512*512
    const int nblk  = (total >> 18) << 9;  // B * 512 blocks (16x32 tiles)

    sdf_direct<<<nblk, 256, 0, stream>>>(mask, out);
}